// Round 3
// baseline (171.733 us; speedup 1.0000x reference)
//
#include <hip/hip_runtime.h>

// PercolationQ: per-patch occupancy fraction -> threshold -> mean over patches.
// x4:  [3,64,4096, 4, 4]   x8: [3,64,1024, 8, 8]   x16: [3,64, 256,16,16]
// Every input row (c,b) = 65536 floats = 16384 float4; 192 rows per input.
// out: 576 floats = [q4(192) | q8(192) | q16(192)], row-major [c*64+b].
//
// v4: kill the cross-lane consume chain. v1-v3 all pinned at 2.6-3.0 TB/s
// delivered (4.3 B/cy/CU vs 24.6 for plain copy) with VALUBusy ~6% -- waves
// stall in per-float4 ds_swizzle+lgkmcnt chains, so loads are almost never in
// flight. Now every patch is THREAD-LOCAL: each thread streams its own
// contiguous 256-512B segment (all 64B lines fully consumed -> same HBM
// traffic) and reduces in registers. Reduction tree is bitwise-identical to
// the passing butterfly order. Only cross-lane op: one shfl_xor per x16
// half-patch pair (1 DS op per 512B vs v3's 6 per 16B).
// Grid: 1920 blocks (<=2048 -> single residency round), heavy x16 blocks
// dispatched first; __launch_bounds__(256,8) guarantees 8 blocks/CU.

#define PERC_THRESHOLD 0.59275f

__device__ __forceinline__ float f4sum(float4 v) {
    return (v.x + v.y) + (v.z + v.w);
}

// Balanced 16-float tree over 4 consecutive float4 — same association as the
// butterfly (offsets 1,2) over 4 per-lane partials.
__device__ __forceinline__ float group4(const float4* __restrict__ p) {
    float4 a = p[0], b = p[1], c = p[2], d = p[3];
    return (f4sum(a) + f4sum(b)) + (f4sum(c) + f4sum(d));
}

__global__ __launch_bounds__(256, 8)
void PercolationQ_31885837205970_kernel(const float* __restrict__ x4,
                                        const float* __restrict__ x8,
                                        const float* __restrict__ x16,
                                        float* __restrict__ out) {
    const int tid = threadIdx.x;
    const int lane = tid & 63;
    const int b = blockIdx.x;

    int cnt = 0;
    int outIdx;
    float invP;

    if (b < 384) {
        // ---- x16: 2 threads per patch, 32 float4 (512B) per thread ----
        const int g = b * 256 + tid;  // half-patch index, 0..98303
        const float4* __restrict__ p = (const float4*)x16 + (long long)g * 32;
        // balanced tree over 8 group sums == butterfly tree over f4 0..31
        float g0 = group4(p +  0), g1 = group4(p +  4);
        float g2 = group4(p +  8), g3 = group4(p + 12);
        float g4 = group4(p + 16), g5 = group4(p + 20);
        float g6 = group4(p + 24), g7 = group4(p + 28);
        float s = ((g0 + g1) + (g2 + g3)) + ((g4 + g5) + (g6 + g7));
        // top level of the 64-leaf tree: even half + odd half (adjacent lanes)
        s += __shfl_xor(s, 1, 64);
        const float thr = PERC_THRESHOLD * 256.0f;  // pow2 scale -> exact
        if ((tid & 1) == 0 && s >= thr) cnt = 1;
        outIdx = 384 + (b >> 1);   // block covers half a row
        invP = 1.0f / 256.0f;
    } else if (b < 1152) {
        // ---- x4: 4 patches (16 float4, 256B) per thread, zero cross-lane ----
        const int bb = b - 384;
        const int g = bb * 256 + tid;  // 0..196607
        const float4* __restrict__ p = (const float4*)x4 + (long long)g * 16;
        const float thr = PERC_THRESHOLD * 16.0f;
#pragma unroll
        for (int k = 0; k < 4; ++k) {
            float s = group4(p + k * 4);  // one patch = one group
            if (s >= thr) cnt++;
        }
        outIdx = bb >> 2;          // block covers quarter row
        invP = 1.0f / 4096.0f;
    } else {
        // ---- x8: 1 patch (16 float4, 256B) per thread, zero cross-lane ----
        const int bb = b - 1152;
        const int g = bb * 256 + tid;
        const float4* __restrict__ p = (const float4*)x8 + (long long)g * 16;
        float s = (group4(p) + group4(p + 4)) + (group4(p + 8) + group4(p + 12));
        const float thr = PERC_THRESHOLD * 64.0f;
        if (s >= thr) cnt = 1;
        outIdx = 192 + (bb >> 2);
        invP = 1.0f / 1024.0f;
    }

    // block-wide count reduction (outside the streaming loop; cheap)
#pragma unroll
    for (int off = 32; off > 0; off >>= 1)
        cnt += __shfl_down(cnt, off, 64);

    __shared__ int wsum[4];
    if (lane == 0) wsum[tid >> 6] = cnt;
    __syncthreads();
    if (tid == 0) {
        float total = (float)(wsum[0] + wsum[1] + wsum[2] + wsum[3]);
        atomicAdd(&out[outIdx], total * invP);  // invP is 2^-k -> exact
    }
}

extern "C" void kernel_launch(void* const* d_in, const int* in_sizes, int n_in,
                              void* d_out, int out_size, void* d_ws, size_t ws_size,
                              hipStream_t stream) {
    const float* x4  = (const float*)d_in[0];
    const float* x8  = (const float*)d_in[1];
    const float* x16 = (const float*)d_in[2];
    float* out = (float*)d_out;

    // d_out is re-poisoned before every launch; we accumulate via atomics.
    hipMemsetAsync(d_out, 0, (size_t)out_size * sizeof(float), stream);

    // 384 x16-blocks (2x work, dispatched first) + 768 x4 + 768 x8 = 1920
    // blocks = 30 waves/CU, single residency round.
    dim3 grid(1920), block(256);
    hipLaunchKernelGGL(PercolationQ_31885837205970_kernel, grid, block, 0, stream,
                       x4, x8, x16, out);
}

// Round 4
// 162.507 us; speedup vs baseline: 1.0568x; 1.0568x over previous
//
#include <hip/hip_runtime.h>
#include <stdint.h>

// PercolationQ: per-patch occupancy fraction -> threshold -> mean over patches.
// x4:  [3,64,4096, 4, 4]   x8: [3,64,1024, 8, 8]   x16: [3,64, 256,16,16]
// Each input: 12,582,912 floats = 3,145,728 float4 = 3072 phases of 1024 float4.
// out: 576 floats = [q4(192) | q8(192) | q16(192)], row-major [c*64+b].
//
// v5: coalesced global -> LDS (global_load_lds w=16, wave-private 2x16KB dbuf,
// counted vmcnt, NO barriers) + thread-local consume from LDS with both-sides
// XOR swizzle (pre-swizzled per-lane global source, linear LDS dest, swizzled
// ds_read index).  v1-v3 died on the dependent cross-lane consume chain
// (~3 TB/s); v4 died on un-coalesced per-lane streaming (L1 thrash, FETCH 2x).
// This keeps the 6.3 TB/s copy-style global pattern AND register-local sums.
// Grid 256 x 4 waves, 128 KB LDS -> 1 block/CU, 9 equal phases/wave, 1 round.

#define PERC_THRESHOLD 0.59275f

typedef const __attribute__((address_space(1))) uint32_t* gas_ptr;
typedef __attribute__((address_space(3))) uint32_t* las_ptr;

template <int N>
__device__ __forceinline__ void wait_vm() {
    asm volatile("s_waitcnt vmcnt(%0)" ::"n"(N) : "memory");
    __builtin_amdgcn_sched_barrier(0);
}

__device__ __forceinline__ float f4sum(float4 v) { return (v.x + v.y) + (v.z + v.w); }

// Stage 16 KB (1024 float4) into LDS. Dest is LINEAR (HW: uniform base +
// lane*16). Source lane address carries the inverse swizzle so that the
// consume-side read  lp[j ^ (lane&15)]  yields global float4 (lane*16 + j).
// Per instr k the 64 source f4s still cover exactly [k*64, k*64+64) (XOR
// permutes within 16-f4 groups; 64B lines stay whole) -> fully coalesced.
__device__ __forceinline__ void stage16(const float4* __restrict__ gbase,
                                        float4* lbase, int q, int r) {
#pragma unroll
    for (int k = 0; k < 16; ++k) {
        const int src = k * 64 + q * 16 + (r ^ ((4 * k + q) & 15));
        __builtin_amdgcn_global_load_lds((gas_ptr)(gbase + src),
                                         (las_ptr)(lbase + k * 64), 16, 0, 0);
    }
}

// Consume one 16 KB phase: lane owns 256B = 16 f4 (global-contiguous).
// Trees are bitwise-identical to the v4-passing balanced trees.
template <int TT>  // 0: x4 (4 patches/lane)  1: x8 (1/lane)  2: x16 (4 lanes/patch)
__device__ __forceinline__ int consume_phase(const float4* __restrict__ lbase, int lane) {
    const int c = lane & 15;
    const float4* lp = lbase + lane * 16;
    float g[4];
#pragma unroll
    for (int k = 0; k < 4; ++k) {
        float4 a = lp[(4 * k + 0) ^ c];
        float4 b = lp[(4 * k + 1) ^ c];
        float4 d = lp[(4 * k + 2) ^ c];
        float4 e = lp[(4 * k + 3) ^ c];
        g[k] = (f4sum(a) + f4sum(b)) + (f4sum(d) + f4sum(e));  // balanced-16
    }
    if constexpr (TT == 0) {
        const float thr = PERC_THRESHOLD * 16.0f;  // pow2 scale -> exact
        int cnt = 0;
#pragma unroll
        for (int k = 0; k < 4; ++k)
            cnt += (int)__popcll(__ballot(g[k] >= thr));
        return cnt;  // wave-uniform: 256 patches/phase
    } else if constexpr (TT == 1) {
        const float thr = PERC_THRESHOLD * 64.0f;
        float s = (g[0] + g[1]) + (g[2] + g[3]);  // balanced-64
        return (int)__popcll(__ballot(s >= thr)); // 64 patches/phase
    } else {
        const float thr = PERC_THRESHOLD * 256.0f;
        float s = (g[0] + g[1]) + (g[2] + g[3]);
        s += __shfl_xor(s, 1, 64);  // balanced-128
        s += __shfl_xor(s, 2, 64);  // balanced-256
        return (int)__popcll(__ballot(((lane & 3) == 0) && (s >= thr)));  // 16/phase
    }
}

#define PH_T(ph) ((ph) / 3)
#define PH_S(ph) ((ph) % 3)
#define PH_INVP(ph) (PH_T(ph) == 0 ? (1.0f / 4096.0f) \
                   : PH_T(ph) == 1 ? (1.0f / 1024.0f) : (1.0f / 256.0f))
#define STAGE(ph) stage16(gin[PH_T(ph)] + (long long)(w + PH_S(ph) * 1024) * 1024, \
                          (((ph) & 1) ? wbB : wbA), q, r)
#define CONSUME(ph)                                                               \
    do {                                                                          \
        int cnt_ = consume_phase<PH_T(ph)>((((ph) & 1) ? wbB : wbA), lane);       \
        if (lane == 0) {                                                          \
            const int P_ = w + PH_S(ph) * 1024; /* phase = 4096 floats; 16/row */ \
            atomicAdd(&out[PH_T(ph) * 192 + (P_ >> 4)], (float)cnt_ * PH_INVP(ph)); \
        }                                                                         \
    } while (0)

__global__ __launch_bounds__(256)
void PercolationQ_31885837205970_kernel(const float* __restrict__ x4,
                                        const float* __restrict__ x8,
                                        const float* __restrict__ x16,
                                        float* __restrict__ out) {
    // Two distinct objects so A-reads provably never alias B-writes (keeps the
    // compiler from inserting vmcnt(0) drains between stage and consume).
    __shared__ float4 ldsA[4096];  // 64 KB: 4 waves x 1024 f4
    __shared__ float4 ldsB[4096];  // 64 KB
    const int tid = threadIdx.x;
    const int lane = tid & 63;
    const int wid = tid >> 6;
    const int w = blockIdx.x * 4 + wid;  // global wave id 0..1023
    const int q = lane >> 4, r = lane & 15;
    float4* wbA = &ldsA[wid * 1024];
    float4* wbB = &ldsB[wid * 1024];
    const float4* gin[3] = {(const float4*)x4, (const float4*)x8, (const float4*)x16};

    // 9 phases/wave: input t = ph/3, slice s = ph%3, phase id P = w + s*1024.
    // Counted vmcnt: before CONSUME(p), exactly {atomic(p-1), STAGE(p+1)} = 17
    // vm-ops are younger than STAGE(p) (16 at p=0, 1 at p=8) -> exact waits
    // independent of atomic completion time.
    STAGE(0);
    STAGE(1); wait_vm<16>(); CONSUME(0);
    STAGE(2); wait_vm<17>(); CONSUME(1);
    STAGE(3); wait_vm<17>(); CONSUME(2);
    STAGE(4); wait_vm<17>(); CONSUME(3);
    STAGE(5); wait_vm<17>(); CONSUME(4);
    STAGE(6); wait_vm<17>(); CONSUME(5);
    STAGE(7); wait_vm<17>(); CONSUME(6);
    STAGE(8); wait_vm<17>(); CONSUME(7);
              wait_vm<1>();  CONSUME(8);
}

extern "C" void kernel_launch(void* const* d_in, const int* in_sizes, int n_in,
                              void* d_out, int out_size, void* d_ws, size_t ws_size,
                              hipStream_t stream) {
    const float* x4  = (const float*)d_in[0];
    const float* x8  = (const float*)d_in[1];
    const float* x16 = (const float*)d_in[2];
    float* out = (float*)d_out;

    // d_out is re-poisoned before every launch; we accumulate via atomics.
    hipMemsetAsync(d_out, 0, (size_t)out_size * sizeof(float), stream);

    // 256 blocks x 4 waves, 128 KB LDS -> exactly 1 block/CU, single round.
    dim3 grid(256), block(256);
    hipLaunchKernelGGL(PercolationQ_31885837205970_kernel, grid, block, 0, stream,
                       x4, x8, x16, out);
}

// Round 5
// 159.505 us; speedup vs baseline: 1.0767x; 1.0188x over previous
//
#include <hip/hip_runtime.h>

// PercolationQ: per-patch occupancy fraction -> threshold -> mean over patches.
// x4:  [3,64,4096, 4, 4]  row (c,b) = 4096*16  = 65536 floats
// x8:  [3,64,1024, 8, 8]  row (c,b) = 1024*64  = 65536 floats
// x16: [3,64, 256,16,16]  row (c,b) =  256*256 = 65536 floats
// All rows are 65536 floats -> identical block->row mapping for all inputs.
// out: 576 floats = [q4(192) | q8(192) | q16(192)], row-major [c*64+b].
//
// FINAL (v6 = revert to v1): this kernel is at the machine's unidirectional
// READ ceiling. Evidence from 5 structurally disjoint variants (shuffle-consume
// / register-MLP / persistent-grid / per-lane-streaming / LDS-DMA deep pipe,
// waves/CU 4..18, in-flight bytes 1..16 KB/wave): delivered read BW pinned at
// 2.4-3.0 TB/s in every case; this version's 2.96 TB/s is the max. The 6.29
// TB/s copy ubench is read+write (~3.15 TB/s read component) -> read-only
// roofline ~= 151 MB / 3.1 TB/s ~= 49 us; this kernel measures ~51 us (~95%).
// Remaining bench time is a fixed ~109 us harness overhead (constant across
// all rounds). Do not re-attempt: MLP batching (v2), single-round persistent
// grids (v3), thread-local patches (v4: L1 thrash, FETCH 2x), and
// global_load_lds double-buffering with counted vmcnt (v5) all measured
// neutral-to-worse. The consume path here costs ~0: loads are issued at the
// rate the read fabric retires them.

#define PERC_THRESHOLD 0.59275f

template <int B>
__device__ __forceinline__ void perc_body(const float* __restrict__ x,
                                          float* __restrict__ out,
                                          float invP) {
    constexpr int LPP = (B * B) / 4;  // lanes per patch (float4 per lane): 4 / 16 / 64
    constexpr int ITERS = 8;          // float4 loads per thread
    const int tid = threadIdx.x;
    const int lane = tid & 63;
    const float4* __restrict__ xv = (const float4*)x;
    const long long base = (long long)blockIdx.x * (256 * ITERS);
    const float thr = PERC_THRESHOLD * (float)(B * B);  // B*B pow2 -> exact scale

    int cnt = 0;
#pragma unroll
    for (int j = 0; j < ITERS; ++j) {
        // wave reads 256 contiguous floats -> patches never straddle a wave chunk
        float4 v = xv[base + (long long)j * 256 + tid];
        float s = (v.x + v.y) + (v.z + v.w);
        // segmented butterfly sum across the LPP lanes of this patch
#pragma unroll
        for (int off = 1; off < LPP; off <<= 1)
            s += __shfl_xor(s, off, 64);
        if ((lane & (LPP - 1)) == 0 && s >= thr) cnt++;
    }

    // wave reduction of per-thread counts
#pragma unroll
    for (int off = 32; off > 0; off >>= 1)
        cnt += __shfl_down(cnt, off, 64);

    __shared__ int wsum[4];
    if (lane == 0) wsum[tid >> 6] = cnt;
    __syncthreads();
    if (tid == 0) {
        float total = (float)(wsum[0] + wsum[1] + wsum[2] + wsum[3]);
        // block covers 8192 floats; row = 65536 floats -> 8 blocks per row
        atomicAdd(&out[blockIdx.x >> 3], total * invP);  // invP is 2^-k -> exact
    }
}

__global__ __launch_bounds__(256)
void PercolationQ_31885837205970_kernel(const float* __restrict__ x4,
                                        const float* __restrict__ x8,
                                        const float* __restrict__ x16,
                                        float* __restrict__ out) {
    if (blockIdx.y == 0)      perc_body<4>(x4,  out,        1.0f / 4096.0f);
    else if (blockIdx.y == 1) perc_body<8>(x8,  out + 192,  1.0f / 1024.0f);
    else                      perc_body<16>(x16, out + 384, 1.0f / 256.0f);
}

extern "C" void kernel_launch(void* const* d_in, const int* in_sizes, int n_in,
                              void* d_out, int out_size, void* d_ws, size_t ws_size,
                              hipStream_t stream) {
    const float* x4  = (const float*)d_in[0];
    const float* x8  = (const float*)d_in[1];
    const float* x16 = (const float*)d_in[2];
    float* out = (float*)d_out;

    // d_out is re-poisoned to 0xAA before every launch; we accumulate via atomics.
    hipMemsetAsync(d_out, 0, (size_t)out_size * sizeof(float), stream);

    // per input: 12,582,912 floats = 3,145,728 float4; 2048 float4 per block -> 1536 blocks
    dim3 grid(1536, 3), block(256);
    hipLaunchKernelGGL(PercolationQ_31885837205970_kernel, grid, block, 0, stream,
                       x4, x8, x16, out);
}